// Round 11
// baseline (328.942 us; speedup 1.0000x reference)
//
#include <hip/hip_runtime.h>
#include <hip/hip_bf16.h>
#include <hip/hip_cooperative_groups.h>

namespace cg = cooperative_groups;

#define B_   32
#define L_   1024
#define LH_  512
#define CH_  1000
#define PRED_ 192
#define ITERS_ 50
#define KBL_ 16384   // B_*LH_
#define SLOTS_ 1012
#define NTILES_ 253
#define NT2_ 506     // 2-slot tiles for k5
#define NTRI_ 36     // upper-triangle 8x8 tile pairs
#define SEG_ 16      // L-segments for stats partials
#define KMB_ 32      // k-means blocks
#define KMP_ 32      // points per k-means block

typedef __attribute__((ext_vector_type(8))) _Float16 f16x8;
typedef __attribute__((ext_vector_type(4))) float f32x4;

__device__ inline ushort f2h(float x) {
    union { _Float16 h; ushort u; } c;
    c.h = (_Float16)x;
    return c.u;
}

// ---------------- K1: stats partials (blocks 0..511) + weight pack (512+) ---
__global__ __launch_bounds__(256) void k1_fused(const float* __restrict__ x,
                                                float* __restrict__ pS,
                                                float* __restrict__ pSS,
                                                const float* __restrict__ Wg,
                                                const float* __restrict__ Wu,
                                                ushort* __restrict__ WF2) {
    int bx = blockIdx.x;
    int t = threadIdx.x;
    if (bx < 512) {
        int seg = bx & 15;       // 0..15
        int b = bx >> 4;         // 0..31
        if (t >= 250) return;
        int c4 = t * 4;
        const float* xp = x + (size_t)b * L_ * CH_ + (size_t)seg * 64 * CH_ + c4;
        float4 s = {0.f, 0.f, 0.f, 0.f}, ss = {0.f, 0.f, 0.f, 0.f};
#pragma unroll 4
        for (int l = 0; l < 64; ++l) {
            float4 v = *(const float4*)(xp + (size_t)l * CH_);
            s.x += v.x; s.y += v.y; s.z += v.z; s.w += v.w;
            ss.x += v.x * v.x; ss.y += v.y * v.y; ss.z += v.z * v.z; ss.w += v.w * v.w;
        }
        size_t o = ((size_t)seg * B_ + b) * CH_ + c4;
        *(float4*)(pS + o) = s;
        *(float4*)(pSS + o) = ss;
    } else {
        int r = bx - 512;            // 0..575 = lab*192+p
        int p = r % PRED_;
#pragma unroll
        for (int i = 0; i < 4; ++i) {
            int k = i * 256 + t;     // 0..1023
            float w = (k < 512) ? Wg[(size_t)r * LH_ + k]
                                : Wu[(size_t)p * LH_ + (k - 512)];
            WF2[(size_t)r * 1024 + k] = f2h(w);
        }
    }
}

// ---------------- K1b: reduce partials -> mean / std ------------------------
__global__ __launch_bounds__(256) void k1b_reduce(const float* __restrict__ pS,
                                                  const float* __restrict__ pSS,
                                                  float* __restrict__ meanT,
                                                  float* __restrict__ sstdT,
                                                  float* __restrict__ invT) {
    int idx = blockIdx.x * 256 + threadIdx.x;
    if (idx >= B_ * CH_) return;
    int c = idx % CH_;
    int b = idx / CH_;
    float s = 0.f, ss = 0.f;
#pragma unroll
    for (int seg = 0; seg < SEG_; ++seg) {
        size_t o = ((size_t)seg * B_ + b) * CH_ + c;
        s += pS[o];
        ss += pSS[o];
    }
    float m = s * (1.0f / L_);
    float var = (ss - (float)L_ * m * m) * (1.0f / (L_ - 1)) + 1e-5f;
    float sd = sqrtf(var);
    meanT[c * B_ + b] = m;
    sstdT[c * B_ + b] = sd;
    invT[c * B_ + b] = 1.0f / sd;
}

// ---------------- K2: build fp16 z_L + z_U in [n][b][lh] layout -------------
__global__ __launch_bounds__(256) void k2_build(const float* __restrict__ x,
                                                const float* __restrict__ meanT,
                                                const float* __restrict__ invT,
                                                ushort* __restrict__ zLF,
                                                ushort* __restrict__ zUF) {
    __shared__ float Ls[32][33];
    __shared__ float Us[32][33];
    int tid = threadIdx.x;
    int tx = tid & 31, ty = tid >> 5;
    int n0 = blockIdx.x * 32;
    int lh0 = blockIdx.y * 32;
    int b = blockIdx.z;
    int n = n0 + tx;
    float m = 0.f, iv = 0.f;
    if (n < CH_) { m = meanT[n * B_ + b]; iv = invT[n * B_ + b]; }
    for (int r = 0; r < 4; ++r) {
        int lh = lh0 + ty + 8 * r;
        float v0 = 0.f, v1 = 0.f;
        if (n < CH_) {
            v0 = x[((size_t)b * L_ + 2 * lh) * CH_ + n];
            v1 = x[((size_t)b * L_ + 2 * lh + 1) * CH_ + n];
        }
        float a = (v0 - m) * iv * 0.5f;
        float c2 = (v1 - m) * iv * 0.5f;
        Ls[ty + 8 * r][tx] = a + c2;
        Us[ty + 8 * r][tx] = a - c2;
    }
    __syncthreads();
    for (int r = 0; r < 4; ++r) {
        int nl = ty + 8 * r;
        int nn = n0 + nl;
        if (nn < CH_) {
            size_t dst = (size_t)nn * KBL_ + (size_t)b * LH_ + lh0 + tx;
            zLF[dst] = f2h(Ls[tx][nl]);
            zUF[dst] = f2h(Us[tx][nl]);
        }
    }
}

// ---------------- K3: symmetric Gram fp16 MFMA + fused last-block reduce ----
#define ZSPLIT_ 16
#define KSEG_   1024
#define NT_     (KSEG_ / 32)

__global__ __launch_bounds__(256) void k3_mfma(const ushort* __restrict__ zF,
                                               float* __restrict__ gpart,
                                               float* __restrict__ g,
                                               int* __restrict__ tilecnt) {
    __shared__ __align__(16) ushort AH[128][40];
    __shared__ __align__(16) ushort BH[128][40];
    __shared__ int doneS;

    int bid = blockIdx.x;
    int xcd = bid & 7, w = bid >> 3;           // w in 0..71
    int ksl = 2 * xcd + (w >= NTRI_);
    int t = (w >= NTRI_) ? w - NTRI_ : w;
    int ti = 0, tt = t;
    while (tt >= 8 - ti) { tt -= 8 - ti; ++ti; }
    int tj = ti + tt;
    int i0 = ti * 128, j0 = tj * 128;
    int kb = ksl * KSEG_;

    int tid = threadIdx.x;
    int lane = tid & 63;
    int wid = tid >> 6;
    int wr = wid >> 1, wc = wid & 1;
    int fr = lane & 15;
    int g8 = lane >> 4;

    f32x4 acc[4][4];
#pragma unroll
    for (int m = 0; m < 4; ++m)
#pragma unroll
        for (int n = 0; n < 4; ++n) acc[m][n] = (f32x4){0.f, 0.f, 0.f, 0.f};

    int srow = tid >> 2;
    int sseg = tid & 3;

    uint4 pv[4];
    auto stage_load = [&](int kt) {
        int k0 = kb + kt * 32;
#pragma unroll
        for (int s = 0; s < 4; ++s) {
            int tile = s >> 1, rep = s & 1;
            int row = srow + rep * 64;
            int grow = ((tile == 0) ? i0 : j0) + row;
            uint4 v = {0u, 0u, 0u, 0u};
            if (grow < CH_)
                v = *(const uint4*)(zF + (size_t)grow * KBL_ + k0 + sseg * 8);
            pv[s] = v;
        }
    };
    auto stage_write = [&]() {
#pragma unroll
        for (int s = 0; s < 4; ++s) {
            int tile = s >> 1, rep = s & 1;
            int row = srow + rep * 64;
            ushort* dst = (tile == 0) ? &AH[row][sseg * 8] : &BH[row][sseg * 8];
            *(uint4*)dst = pv[s];
        }
    };

    stage_load(0);
    for (int t2 = 0; t2 < NT_; ++t2) {
        __syncthreads();
        stage_write();
        __syncthreads();
        if (t2 + 1 < NT_) stage_load(t2 + 1);

        f16x8 a[4];
#pragma unroll
        for (int m = 0; m < 4; ++m)
            a[m] = *(const f16x8*)&AH[wr * 64 + m * 16 + fr][g8 * 8];
#pragma unroll
        for (int n = 0; n < 4; ++n) {
            f16x8 bv = *(const f16x8*)&BH[wc * 64 + n * 16 + fr][g8 * 8];
#pragma unroll
            for (int m = 0; m < 4; ++m)
                acc[m][n] = __builtin_amdgcn_mfma_f32_16x16x32_f16(a[m], bv, acc[m][n], 0, 0, 0);
        }
    }

    float* gp = gpart + ((size_t)ksl * NTRI_ + t) * 16384;
#pragma unroll
    for (int m = 0; m < 4; ++m) {
        int rb = wr * 64 + m * 16 + g8 * 4;
#pragma unroll
        for (int n = 0; n < 4; ++n) {
            int c = wc * 64 + n * 16 + fr;
#pragma unroll
            for (int q = 0; q < 4; ++q)
                gp[(size_t)(rb + q) * 128 + c] = acc[m][n][q];
        }
    }

    // ---- last block for this tile reduces the 16 partials (fixed order) ----
    __threadfence();                     // release: partial visible device-wide
    if (tid == 0) doneS = atomicAdd(&tilecnt[t], 1);
    __syncthreads();
    if (doneS != ZSPLIT_ - 1) return;
    __threadfence();                     // acquire: see all partials

#pragma unroll
    for (int seg = 0; seg < 4; ++seg) {
        int e0 = seg * 4096 + tid * 16;
        int r = e0 >> 7, c0 = e0 & 127;
        float4 s[4];
#pragma unroll
        for (int j = 0; j < 4; ++j) s[j] = (float4){0.f, 0.f, 0.f, 0.f};
#pragma unroll
        for (int p = 0; p < ZSPLIT_; ++p) {
            const float* src = gpart + ((size_t)p * NTRI_ + t) * 16384 + e0;
#pragma unroll
            for (int j = 0; j < 4; ++j) {
                float4 v = *(const float4*)(src + j * 4);
                s[j].x += v.x; s[j].y += v.y; s[j].z += v.z; s[j].w += v.w;
            }
        }
        int i = i0 + r;
        if (i < CH_) {
#pragma unroll
            for (int j = 0; j < 4; ++j) {
                int jc = j0 + c0 + j * 4;
                if (jc + 3 < CH_) {
                    *(float4*)(g + (size_t)i * CH_ + jc) = s[j];
                } else {
#pragma unroll
                    for (int e = 0; e < 4; ++e)
                        if (jc + e < CH_) g[(size_t)i * CH_ + jc + e] = ((const float*)&s[j])[e];
                }
            }
            if (ti != tj) {
#pragma unroll
                for (int j = 0; j < 4; ++j) {
#pragma unroll
                    for (int e = 0; e < 4; ++e) {
                        int jc = j0 + c0 + j * 4 + e;
                        if (jc < CH_) g[(size_t)jc * CH_ + i] = ((const float*)&s[j])[e];
                    }
                }
            }
        }
    }
}

// ---------------- K4: cooperative k-means, G rows LDS-cached ----------------
__global__ __launch_bounds__(1024) void k4_kmeans(const float* __restrict__ g,
                                                  float* __restrict__ sbuf,
                                                  int* __restrict__ chlist,
                                                  int* __restrict__ chpos,
                                                  int* __restrict__ slabel) {
    cg::grid_group grid = cg::this_grid();
    __shared__ float gl[KMP_ * CH_];     // 125 KB: this block's 32 G rows
    __shared__ int   lab[1024];
    __shared__ float wred[16][3];
    __shared__ float ccS[3];
    __shared__ float ccPrev[3];
    __shared__ int   cntPrev[3];
    __shared__ int   cnt2[3];
    __shared__ int   chgS;
    __shared__ int   st[4], c2r[3];

    int tid = threadIdx.x;
    int wv = tid >> 6, ln64 = tid & 63;
    int bpt0 = blockIdx.x * KMP_;

    {
        int nrow = CH_ - bpt0;
        if (nrow > KMP_) nrow = KMP_;
        if (nrow < 0) nrow = 0;
        int nf4 = nrow * (CH_ / 4);
        const float4* gsrc = (const float4*)(g + (size_t)bpt0 * CH_);
        float4* gdst = (float4*)gl;
        for (int i = tid; i < nf4; i += 1024) gdst[i] = gsrc[i];
    }

    int lbp = (tid < 3) ? tid : 3;      // sentinel 3 = unassigned
    lab[tid] = lbp;
    if (tid < 3) {
        cntPrev[tid] = 1;
        ccPrev[tid] = g[(size_t)tid * CH_ + tid];
    }
    __syncthreads();

    int par = 0;
    for (int it = 1; it <= ITERS_ + 1; ++it) {
        const float* sp = sbuf + par * 3 * CH_;
        float s0 = 0.f, s1 = 0.f, s2 = 0.f;
        if (tid < CH_) {
            if (it == 1) {
                const float* gr = g + (size_t)tid * CH_;
                s0 = gr[0]; s1 = gr[1]; s2 = gr[2];
            } else {
                s0 = sp[tid * 3 + 0]; s1 = sp[tid * 3 + 1]; s2 = sp[tid * 3 + 2];
            }
        }
        float c0 = (lbp == 0) ? s0 : 0.f;
        float c1 = (lbp == 1) ? s1 : 0.f;
        float c2 = (lbp == 2) ? s2 : 0.f;
#pragma unroll
        for (int m = 1; m < 64; m <<= 1) {
            c0 += __shfl_xor(c0, m);
            c1 += __shfl_xor(c1, m);
            c2 += __shfl_xor(c2, m);
        }
        if (ln64 == 0) { wred[wv][0] = c0; wred[wv][1] = c1; wred[wv][2] = c2; }
        if (tid == 0) { cnt2[0] = 0; cnt2[1] = 0; cnt2[2] = 0; chgS = 0; }
        __syncthreads();
        if (tid < 3) {
            float sacc = 0.f;
#pragma unroll
            for (int w2 = 0; w2 < 16; ++w2) sacc += wred[w2][tid];
            int n = cntPrev[tid];
            float cc = (n > 0) ? sacc / (float)n : ccPrev[tid];
            ccS[tid] = cc;
            ccPrev[tid] = cc;
        }
        __syncthreads();
        float cc0 = ccS[0], cc1 = ccS[1], cc2 = ccS[2];

        int nl = lbp;
        if (tid < CH_) {
            float d0 = cc0 - 2.f * s0;
            float d1 = cc1 - 2.f * s1;
            float d2 = cc2 - 2.f * s2;
            nl = 0; float dm = d0;
            if (d1 < dm) { dm = d1; nl = 1; }
            if (d2 < dm) { dm = d2; nl = 2; }
        }
        bool act = (tid < CH_);
        unsigned long long b0 = __ballot(act && nl == 0);
        unsigned long long b1 = __ballot(act && nl == 1);
        unsigned long long b2 = __ballot(act && nl == 2);
        unsigned long long bc = __ballot(act && nl != lbp);
        if (ln64 == 0) {
            if (b0) atomicAdd(&cnt2[0], (int)__popcll(b0));
            if (b1) atomicAdd(&cnt2[1], (int)__popcll(b1));
            if (b2) atomicAdd(&cnt2[2], (int)__popcll(b2));
            if (bc) atomicAdd(&chgS, (int)__popcll(bc));
        }
        lab[tid] = nl;
        lbp = nl;
        __syncthreads();

        if (it == ITERS_ + 1) break;
        if (chgS == 0 && it > 1) break;

        int n0n = cnt2[0], n1n = cnt2[1], n2n = cnt2[2];
        float* sq = sbuf + (par ^ 1) * 3 * CH_;
        int pl = tid >> 5;
        int ln = tid & 31;
        int i = bpt0 + pl;
        if (i < CH_) {
            const float* gr = gl + pl * CH_;
            float a0 = 0.f, a1 = 0.f, a2 = 0.f;
            for (int j = ln; j < CH_; j += 32) {
                float gv = gr[j];
                int lb = lab[j];
                a0 += (lb == 0) ? gv : 0.f;
                a1 += (lb == 1) ? gv : 0.f;
                a2 += (lb == 2) ? gv : 0.f;
            }
#pragma unroll
            for (int msk = 1; msk < 32; msk <<= 1) {
                a0 += __shfl_xor(a0, msk, 32);
                a1 += __shfl_xor(a1, msk, 32);
                a2 += __shfl_xor(a2, msk, 32);
            }
            if (ln == 0) {
                float f0, f1, f2;
                if (it == 1) { f0 = gr[0]; f1 = gr[1]; f2 = gr[2]; }
                else { f0 = sp[i * 3 + 0]; f1 = sp[i * 3 + 1]; f2 = sp[i * 3 + 2]; }
                sq[i * 3 + 0] = (n0n > 0) ? a0 / (float)n0n : f0;
                sq[i * 3 + 1] = (n1n > 0) ? a1 / (float)n1n : f1;
                sq[i * 3 + 2] = (n2n > 0) ? a2 / (float)n2n : f2;
            }
        }
        if (tid < 3) cntPrev[tid] = cnt2[tid];
        par ^= 1;
        grid.sync();
    }

    if (blockIdx.x == 0) {
        if (tid == 0) {
            st[0] = 0;
            st[1] = ((cnt2[0] + 3) >> 2) << 2;
            st[2] = st[1] + (((cnt2[1] + 3) >> 2) << 2);
            st[3] = st[2] + (((cnt2[2] + 3) >> 2) << 2);
            c2r[0] = 0; c2r[1] = 0; c2r[2] = 0;
        }
        __syncthreads();
        if (tid < SLOTS_) chlist[tid] = 0;
        if (tid < NTILES_) {
            int s = tid * 4;
            slabel[tid] = (s < st[1]) ? 0 : (s < st[2]) ? 1 : (s < st[3]) ? 2 : 0;
        }
        __syncthreads();
        if (tid < CH_) {
            int lb = lab[tid];
            int r = atomicAdd(&c2r[lb], 1);
            int slot = st[lb] + r;
            chlist[slot] = tid;
            chpos[tid] = slot;
        }
    }
}

// ---------------- K5: grouped GEMM  C[64 sb][192 p] = Z_tile . WF2[lab]^T ---
__global__ __launch_bounds__(256) void k5_grouped(const ushort* __restrict__ zLF,
                                                  const ushort* __restrict__ zUF,
                                                  const ushort* __restrict__ WF2,
                                                  const int* __restrict__ chlist,
                                                  const int* __restrict__ slabel,
                                                  const float* __restrict__ bg,
                                                  const float* __restrict__ bu,
                                                  const float* __restrict__ meanT,
                                                  const float* __restrict__ sstdT,
                                                  float* __restrict__ outP) {
    __shared__ __align__(16) ushort ZT[64][40];
    __shared__ __align__(16) ushort WT[192][40];
    __shared__ int sch[2];

    int tile = blockIdx.x;               // 0..505
    int tid = threadIdx.x;
    if (tid < 2) sch[tid] = chlist[tile * 2 + tid];
    int lab = slabel[tile >> 1];
    __syncthreads();

    int lane = tid & 63, wid = tid >> 6; // wid = p-quarter (48 p each)
    int fr = lane & 15, g8 = lane >> 4;

    int srow = tid >> 2, sseg = tid & 3; // srow 0..63
    size_t zb = (size_t)sch[srow >> 5] * KBL_ + (size_t)(srow & 31) * LH_;
    const ushort* wbase = WF2 + (size_t)(lab * PRED_) * 1024;

    f32x4 acc[4][3];
#pragma unroll
    for (int m = 0; m < 4; ++m)
#pragma unroll
        for (int n = 0; n < 3; ++n) acc[m][n] = (f32x4){0.f, 0.f, 0.f, 0.f};

    uint4 pz, pw0, pw1, pw2;
    auto stage_load = [&](int t) {
        const ushort* zsrc = (t < 16) ? zLF : zUF;
        int ko = ((t & 15) * 32) + sseg * 8;
        pz  = *(const uint4*)(zsrc + zb + ko);
        int kw = t * 32 + sseg * 8;
        pw0 = *(const uint4*)(wbase + (size_t)srow * 1024 + kw);
        pw1 = *(const uint4*)(wbase + (size_t)(srow + 64) * 1024 + kw);
        pw2 = *(const uint4*)(wbase + (size_t)(srow + 128) * 1024 + kw);
    };
    auto stage_write = [&]() {
        *(uint4*)&ZT[srow][sseg * 8] = pz;
        *(uint4*)&WT[srow][sseg * 8] = pw0;
        *(uint4*)&WT[srow + 64][sseg * 8] = pw1;
        *(uint4*)&WT[srow + 128][sseg * 8] = pw2;
    };

    stage_load(0);
    for (int t = 0; t < 32; ++t) {
        __syncthreads();
        stage_write();
        __syncthreads();
        if (t + 1 < 32) stage_load(t + 1);

        f16x8 a[4];
#pragma unroll
        for (int m = 0; m < 4; ++m)
            a[m] = *(const f16x8*)&ZT[m * 16 + fr][g8 * 8];
#pragma unroll
        for (int nf = 0; nf < 3; ++nf) {
            f16x8 bv = *(const f16x8*)&WT[wid * 48 + nf * 16 + fr][g8 * 8];
#pragma unroll
            for (int m = 0; m < 4; ++m)
                acc[m][nf] = __builtin_amdgcn_mfma_f32_16x16x32_f16(a[m], bv, acc[m][nf], 0, 0, 0);
        }
    }

#pragma unroll
    for (int m = 0; m < 4; ++m) {
#pragma unroll
        for (int q = 0; q < 4; ++q) {
            int sb = m * 16 + g8 * 4 + q;
            int sl = sb >> 5, b = sb & 31;
            int n = sch[sl];
            float sd = sstdT[n * B_ + b], mu = meanT[n * B_ + b];
            size_t obase = ((size_t)(tile * 2 + sl) * B_ + b) * PRED_;
#pragma unroll
            for (int nf = 0; nf < 3; ++nf) {
                int p = wid * 48 + nf * 16 + fr;
                float v = acc[m][nf][q] + bg[lab * PRED_ + p] + bu[p];
                outP[obase + p] = v * sd + mu;
            }
        }
    }
}

// ---------------- K7: unpermute outP -> out[b][p][n] ------------------------
__global__ __launch_bounds__(256) void k7_unperm(const float* __restrict__ outP,
                                                 const int* __restrict__ chpos,
                                                 float* __restrict__ out) {
    int n = blockIdx.x * 256 + threadIdx.x;
    int p0 = blockIdx.y * 32;
    int b = blockIdx.z;
    if (n >= CH_) return;
    const float* src = outP + ((size_t)chpos[n] * B_ + b) * PRED_ + p0;
    float4 v[8];
#pragma unroll
    for (int j = 0; j < 8; ++j) v[j] = *(const float4*)(src + j * 4);
#pragma unroll
    for (int j = 0; j < 8; ++j) {
#pragma unroll
        for (int e = 0; e < 4; ++e) {
            int p = p0 + j * 4 + e;
            out[((size_t)b * PRED_ + p) * CH_ + n] = ((const float*)&v[j])[e];
        }
    }
}

extern "C" void kernel_launch(void* const* d_in, const int* in_sizes, int n_in,
                              void* d_out, int out_size, void* d_ws, size_t ws_size,
                              hipStream_t stream) {
    const float* x  = (const float*)d_in[0];
    const float* Wg = (const float*)d_in[4];
    const float* bg = (const float*)d_in[5];
    const float* Wu = (const float*)d_in[6];
    const float* bu = (const float*)d_in[7];
    float* out = (float*)d_out;
    (void)in_sizes; (void)n_in; (void)out_size; (void)ws_size;

    char* ws = (char*)d_ws;
    size_t off = 0;
    auto alloc = [&](size_t bytes) {
        void* p = ws + off;
        off = (off + bytes + 255) & ~(size_t)255;
        return p;
    };
    ushort* zLF  = (ushort*)alloc((size_t)16384000 * 2);
    ushort* zUF  = (ushort*)alloc((size_t)16384000 * 2);
    float*  G    = (float*)alloc((size_t)1000000 * 4);
    ushort* WF2  = (ushort*)alloc((size_t)576 * 1024 * 2);
    float*  meanT = (float*)alloc((size_t)32000 * 4);
    float*  sstdT = (float*)alloc((size_t)32000 * 4);
    float*  invT  = (float*)alloc((size_t)32000 * 4);
    float*  pS   = (float*)alloc((size_t)SEG_ * B_ * CH_ * 4);
    float*  pSS  = (float*)alloc((size_t)SEG_ * B_ * CH_ * 4);
    float*  sbuf = (float*)alloc((size_t)2 * 3 * CH_ * 4);
    int*    chlist = (int*)alloc((size_t)SLOTS_ * 4);
    int*    chpos  = (int*)alloc((size_t)1024 * 4);
    int*    slabel = (int*)alloc((size_t)256 * 4);
    int*    tilecnt = (int*)alloc((size_t)64 * 4);
    // union region: Gp (16*36*16384*4 = 37.7 MB, dead after k3) then outP (24.9 MB)
    char* unionBase = (char*)alloc((size_t)ZSPLIT_ * NTRI_ * 16384 * 4);
    float* Gp   = (float*)unionBase;
    float* outP = (float*)unionBase;

    hipMemsetAsync(tilecnt, 0, 64 * 4, stream);
    k1_fused<<<512 + 576, 256, 0, stream>>>(x, pS, pSS, Wg, Wu, WF2);
    k1b_reduce<<<125, 256, 0, stream>>>(pS, pSS, meanT, sstdT, invT);
    k2_build<<<dim3(32, 16, 32), 256, 0, stream>>>(x, meanT, invT, zLF, zUF);
    k3_mfma<<<8 * NTRI_ * 2, 256, 0, stream>>>(zLF, Gp, G, tilecnt);
    void* args[] = { (void*)&G, (void*)&sbuf, (void*)&chlist, (void*)&chpos, (void*)&slabel };
    hipLaunchCooperativeKernel((void*)k4_kmeans, dim3(KMB_), dim3(1024), args, 0, stream);
    k5_grouped<<<NT2_, 256, 0, stream>>>(zLF, zUF, WF2, chlist, slabel,
                                         bg, bu, meanT, sstdT, outP);
    k7_unperm<<<dim3(4, 6, 32), 256, 0, stream>>>(outP, chpos, out);
}

// Round 12
// 199.676 us; speedup vs baseline: 1.6474x; 1.6474x over previous
//
#include <hip/hip_runtime.h>
#include <hip/hip_bf16.h>
#include <hip/hip_cooperative_groups.h>

namespace cg = cooperative_groups;

#define B_   32
#define L_   1024
#define LH_  512
#define CH_  1000
#define PRED_ 192
#define ITERS_ 50
#define KBL_ 16384   // B_*LH_
#define SLOTS_ 1012
#define NTILES_ 253
#define NT2_ 506     // 2-slot tiles for k5
#define NTRI_ 36     // upper-triangle 8x8 tile pairs
#define SEG_ 16      // L-segments for stats partials
#define KMB_ 32      // k-means blocks
#define KMP_ 32      // points per k-means block

typedef __attribute__((ext_vector_type(8))) _Float16 f16x8;
typedef __attribute__((ext_vector_type(4))) float f32x4;

__device__ inline ushort f2h(float x) {
    union { _Float16 h; ushort u; } c;
    c.h = (_Float16)x;
    return c.u;
}

// ---------------- K1: stats partials (blocks 0..511) + weight pack (512+) ---
__global__ __launch_bounds__(256) void k1_fused(const float* __restrict__ x,
                                                float* __restrict__ pS,
                                                float* __restrict__ pSS,
                                                const float* __restrict__ Wg,
                                                const float* __restrict__ Wu,
                                                ushort* __restrict__ WF2) {
    int bx = blockIdx.x;
    int t = threadIdx.x;
    if (bx < 512) {
        int seg = bx & 15;       // 0..15
        int b = bx >> 4;         // 0..31
        if (t >= 250) return;
        int c4 = t * 4;
        const float* xp = x + (size_t)b * L_ * CH_ + (size_t)seg * 64 * CH_ + c4;
        float4 s = {0.f, 0.f, 0.f, 0.f}, ss = {0.f, 0.f, 0.f, 0.f};
#pragma unroll 4
        for (int l = 0; l < 64; ++l) {
            float4 v = *(const float4*)(xp + (size_t)l * CH_);
            s.x += v.x; s.y += v.y; s.z += v.z; s.w += v.w;
            ss.x += v.x * v.x; ss.y += v.y * v.y; ss.z += v.z * v.z; ss.w += v.w * v.w;
        }
        size_t o = ((size_t)seg * B_ + b) * CH_ + c4;
        *(float4*)(pS + o) = s;
        *(float4*)(pSS + o) = ss;
    } else {
        int r = bx - 512;            // 0..575 = lab*192+p
        int p = r % PRED_;
#pragma unroll
        for (int i = 0; i < 4; ++i) {
            int k = i * 256 + t;     // 0..1023
            float w = (k < 512) ? Wg[(size_t)r * LH_ + k]
                                : Wu[(size_t)p * LH_ + (k - 512)];
            WF2[(size_t)r * 1024 + k] = f2h(w);
        }
    }
}

// ---------------- K1b: reduce partials -> mean / std ------------------------
__global__ __launch_bounds__(256) void k1b_reduce(const float* __restrict__ pS,
                                                  const float* __restrict__ pSS,
                                                  float* __restrict__ meanT,
                                                  float* __restrict__ sstdT,
                                                  float* __restrict__ invT) {
    int idx = blockIdx.x * 256 + threadIdx.x;
    if (idx >= B_ * CH_) return;
    int c = idx % CH_;
    int b = idx / CH_;
    float s = 0.f, ss = 0.f;
#pragma unroll
    for (int seg = 0; seg < SEG_; ++seg) {
        size_t o = ((size_t)seg * B_ + b) * CH_ + c;
        s += pS[o];
        ss += pSS[o];
    }
    float m = s * (1.0f / L_);
    float var = (ss - (float)L_ * m * m) * (1.0f / (L_ - 1)) + 1e-5f;
    float sd = sqrtf(var);
    meanT[c * B_ + b] = m;
    sstdT[c * B_ + b] = sd;
    invT[c * B_ + b] = 1.0f / sd;
}

// ---------------- K2: build fp16 z_L + z_U in [n][b][lh] layout -------------
__global__ __launch_bounds__(256) void k2_build(const float* __restrict__ x,
                                                const float* __restrict__ meanT,
                                                const float* __restrict__ invT,
                                                ushort* __restrict__ zLF,
                                                ushort* __restrict__ zUF) {
    __shared__ float Ls[32][33];
    __shared__ float Us[32][33];
    int tid = threadIdx.x;
    int tx = tid & 31, ty = tid >> 5;
    int n0 = blockIdx.x * 32;
    int lh0 = blockIdx.y * 32;
    int b = blockIdx.z;
    int n = n0 + tx;
    float m = 0.f, iv = 0.f;
    if (n < CH_) { m = meanT[n * B_ + b]; iv = invT[n * B_ + b]; }
    for (int r = 0; r < 4; ++r) {
        int lh = lh0 + ty + 8 * r;
        float v0 = 0.f, v1 = 0.f;
        if (n < CH_) {
            v0 = x[((size_t)b * L_ + 2 * lh) * CH_ + n];
            v1 = x[((size_t)b * L_ + 2 * lh + 1) * CH_ + n];
        }
        float a = (v0 - m) * iv * 0.5f;
        float c2 = (v1 - m) * iv * 0.5f;
        Ls[ty + 8 * r][tx] = a + c2;
        Us[ty + 8 * r][tx] = a - c2;
    }
    __syncthreads();
    for (int r = 0; r < 4; ++r) {
        int nl = ty + 8 * r;
        int nn = n0 + nl;
        if (nn < CH_) {
            size_t dst = (size_t)nn * KBL_ + (size_t)b * LH_ + lh0 + tx;
            zLF[dst] = f2h(Ls[tx][nl]);
            zUF[dst] = f2h(Us[tx][nl]);
        }
    }
}

// ---------------- K3: symmetric Gram via fp16 MFMA (single-pass) ------------
#define ZSPLIT_ 16
#define KSEG_   1024
#define NT_     (KSEG_ / 32)

__global__ __launch_bounds__(256) void k3_mfma(const ushort* __restrict__ zF,
                                               float* __restrict__ gpart) {
    __shared__ __align__(16) ushort AH[128][40];
    __shared__ __align__(16) ushort BH[128][40];

    int bid = blockIdx.x;
    int xcd = bid & 7, w = bid >> 3;           // w in 0..71
    int ksl = 2 * xcd + (w >= NTRI_);
    int t = (w >= NTRI_) ? w - NTRI_ : w;
    int ti = 0, tt = t;
    while (tt >= 8 - ti) { tt -= 8 - ti; ++ti; }
    int tj = ti + tt;
    int i0 = ti * 128, j0 = tj * 128;
    int kb = ksl * KSEG_;

    int tid = threadIdx.x;
    int lane = tid & 63;
    int wid = tid >> 6;
    int wr = wid >> 1, wc = wid & 1;
    int fr = lane & 15;
    int g8 = lane >> 4;

    f32x4 acc[4][4];
#pragma unroll
    for (int m = 0; m < 4; ++m)
#pragma unroll
        for (int n = 0; n < 4; ++n) acc[m][n] = (f32x4){0.f, 0.f, 0.f, 0.f};

    int srow = tid >> 2;
    int sseg = tid & 3;

    uint4 pv[4];
    auto stage_load = [&](int kt) {
        int k0 = kb + kt * 32;
#pragma unroll
        for (int s = 0; s < 4; ++s) {
            int tile = s >> 1, rep = s & 1;
            int row = srow + rep * 64;
            int grow = ((tile == 0) ? i0 : j0) + row;
            uint4 v = {0u, 0u, 0u, 0u};
            if (grow < CH_)
                v = *(const uint4*)(zF + (size_t)grow * KBL_ + k0 + sseg * 8);
            pv[s] = v;
        }
    };
    auto stage_write = [&]() {
#pragma unroll
        for (int s = 0; s < 4; ++s) {
            int tile = s >> 1, rep = s & 1;
            int row = srow + rep * 64;
            ushort* dst = (tile == 0) ? &AH[row][sseg * 8] : &BH[row][sseg * 8];
            *(uint4*)dst = pv[s];
        }
    };

    stage_load(0);
    for (int t2 = 0; t2 < NT_; ++t2) {
        __syncthreads();
        stage_write();
        __syncthreads();
        if (t2 + 1 < NT_) stage_load(t2 + 1);

        f16x8 a[4];
#pragma unroll
        for (int m = 0; m < 4; ++m)
            a[m] = *(const f16x8*)&AH[wr * 64 + m * 16 + fr][g8 * 8];
#pragma unroll
        for (int n = 0; n < 4; ++n) {
            f16x8 bv = *(const f16x8*)&BH[wc * 64 + n * 16 + fr][g8 * 8];
#pragma unroll
            for (int m = 0; m < 4; ++m)
                acc[m][n] = __builtin_amdgcn_mfma_f32_16x16x32_f16(a[m], bv, acc[m][n], 0, 0, 0);
        }
    }

    float* gp = gpart + ((size_t)ksl * NTRI_ + t) * 16384;
#pragma unroll
    for (int m = 0; m < 4; ++m) {
        int rb = wr * 64 + m * 16 + g8 * 4;
#pragma unroll
        for (int n = 0; n < 4; ++n) {
            int c = wc * 64 + n * 16 + fr;
#pragma unroll
            for (int q = 0; q < 4; ++q)
                gp[(size_t)(rb + q) * 128 + c] = acc[m][n][q];
        }
    }
}

// ---------------- K3b: reduce 16 partials per tile, write G + mirror --------
__global__ __launch_bounds__(256) void k3b_sym(const float* __restrict__ gpart,
                                               float* __restrict__ g) {
    int t = blockIdx.x;          // 0..35
    int seg = blockIdx.y;        // 0..3
    int ti = 0, tt = t;
    while (tt >= 8 - ti) { tt -= 8 - ti; ++ti; }
    int tj = ti + tt;
    int i0 = ti * 128, j0 = tj * 128;
    int tid = threadIdx.x;
    int e0 = seg * 4096 + tid * 16;
    int r = e0 >> 7, c0 = e0 & 127;

    float4 s[4];
#pragma unroll
    for (int j = 0; j < 4; ++j) s[j] = (float4){0.f, 0.f, 0.f, 0.f};
#pragma unroll
    for (int p = 0; p < ZSPLIT_; ++p) {
        const float* src = gpart + ((size_t)p * NTRI_ + t) * 16384 + e0;
#pragma unroll
        for (int j = 0; j < 4; ++j) {
            float4 v = *(const float4*)(src + j * 4);
            s[j].x += v.x; s[j].y += v.y; s[j].z += v.z; s[j].w += v.w;
        }
    }
    int i = i0 + r;
    if (i < CH_) {
#pragma unroll
        for (int j = 0; j < 4; ++j) {
            int jc = j0 + c0 + j * 4;
            if (jc + 3 < CH_) {
                *(float4*)(g + (size_t)i * CH_ + jc) = s[j];
            } else {
#pragma unroll
                for (int e = 0; e < 4; ++e)
                    if (jc + e < CH_) g[(size_t)i * CH_ + jc + e] = ((const float*)&s[j])[e];
            }
        }
        if (ti != tj) {
#pragma unroll
            for (int j = 0; j < 4; ++j) {
#pragma unroll
                for (int e = 0; e < 4; ++e) {
                    int jc = j0 + c0 + j * 4 + e;
                    if (jc < CH_) g[(size_t)jc * CH_ + i] = ((const float*)&s[j])[e];
                }
            }
        }
    }
}

// ---------------- K4: cooperative k-means, G rows LDS-cached ----------------
__global__ __launch_bounds__(1024) void k4_kmeans(const float* __restrict__ g,
                                                  float* __restrict__ sbuf,
                                                  int* __restrict__ chlist,
                                                  int* __restrict__ chpos,
                                                  int* __restrict__ slabel) {
    cg::grid_group grid = cg::this_grid();
    __shared__ float gl[KMP_ * CH_];     // 125 KB: this block's 32 G rows
    __shared__ int   lab[1024];
    __shared__ float wred[16][3];
    __shared__ float ccS[3];
    __shared__ float ccPrev[3];
    __shared__ int   cntPrev[3];
    __shared__ int   cnt2[3];
    __shared__ int   chgS;
    __shared__ int   st[4], c2r[3];

    int tid = threadIdx.x;
    int wv = tid >> 6, ln64 = tid & 63;
    int bpt0 = blockIdx.x * KMP_;

    {
        int nrow = CH_ - bpt0;
        if (nrow > KMP_) nrow = KMP_;
        if (nrow < 0) nrow = 0;
        int nf4 = nrow * (CH_ / 4);
        const float4* gsrc = (const float4*)(g + (size_t)bpt0 * CH_);
        float4* gdst = (float4*)gl;
        for (int i = tid; i < nf4; i += 1024) gdst[i] = gsrc[i];
    }

    int lbp = (tid < 3) ? tid : 3;      // sentinel 3 = unassigned
    lab[tid] = lbp;
    if (tid < 3) {
        cntPrev[tid] = 1;
        ccPrev[tid] = g[(size_t)tid * CH_ + tid];
    }
    __syncthreads();

    int par = 0;
    for (int it = 1; it <= ITERS_ + 1; ++it) {
        const float* sp = sbuf + par * 3 * CH_;
        float s0 = 0.f, s1 = 0.f, s2 = 0.f;
        if (tid < CH_) {
            if (it == 1) {
                const float* gr = g + (size_t)tid * CH_;
                s0 = gr[0]; s1 = gr[1]; s2 = gr[2];
            } else {
                s0 = sp[tid * 3 + 0]; s1 = sp[tid * 3 + 1]; s2 = sp[tid * 3 + 2];
            }
        }
        float c0 = (lbp == 0) ? s0 : 0.f;
        float c1 = (lbp == 1) ? s1 : 0.f;
        float c2 = (lbp == 2) ? s2 : 0.f;
#pragma unroll
        for (int m = 1; m < 64; m <<= 1) {
            c0 += __shfl_xor(c0, m);
            c1 += __shfl_xor(c1, m);
            c2 += __shfl_xor(c2, m);
        }
        if (ln64 == 0) { wred[wv][0] = c0; wred[wv][1] = c1; wred[wv][2] = c2; }
        if (tid == 0) { cnt2[0] = 0; cnt2[1] = 0; cnt2[2] = 0; chgS = 0; }
        __syncthreads();
        if (tid < 3) {
            float sacc = 0.f;
#pragma unroll
            for (int w2 = 0; w2 < 16; ++w2) sacc += wred[w2][tid];
            int n = cntPrev[tid];
            float cc = (n > 0) ? sacc / (float)n : ccPrev[tid];
            ccS[tid] = cc;
            ccPrev[tid] = cc;
        }
        __syncthreads();
        float cc0 = ccS[0], cc1 = ccS[1], cc2 = ccS[2];

        int nl = lbp;
        if (tid < CH_) {
            float d0 = cc0 - 2.f * s0;
            float d1 = cc1 - 2.f * s1;
            float d2 = cc2 - 2.f * s2;
            nl = 0; float dm = d0;
            if (d1 < dm) { dm = d1; nl = 1; }
            if (d2 < dm) { dm = d2; nl = 2; }
        }
        bool act = (tid < CH_);
        unsigned long long b0 = __ballot(act && nl == 0);
        unsigned long long b1 = __ballot(act && nl == 1);
        unsigned long long b2 = __ballot(act && nl == 2);
        unsigned long long bc = __ballot(act && nl != lbp);
        if (ln64 == 0) {
            if (b0) atomicAdd(&cnt2[0], (int)__popcll(b0));
            if (b1) atomicAdd(&cnt2[1], (int)__popcll(b1));
            if (b2) atomicAdd(&cnt2[2], (int)__popcll(b2));
            if (bc) atomicAdd(&chgS, (int)__popcll(bc));
        }
        lab[tid] = nl;
        lbp = nl;
        __syncthreads();

        if (it == ITERS_ + 1) break;
        if (chgS == 0 && it > 1) break;

        int n0n = cnt2[0], n1n = cnt2[1], n2n = cnt2[2];
        float* sq = sbuf + (par ^ 1) * 3 * CH_;
        int pl = tid >> 5;
        int ln = tid & 31;
        int i = bpt0 + pl;
        if (i < CH_) {
            const float* gr = gl + pl * CH_;
            float a0 = 0.f, a1 = 0.f, a2 = 0.f;
            for (int j = ln; j < CH_; j += 32) {
                float gv = gr[j];
                int lb = lab[j];
                a0 += (lb == 0) ? gv : 0.f;
                a1 += (lb == 1) ? gv : 0.f;
                a2 += (lb == 2) ? gv : 0.f;
            }
#pragma unroll
            for (int msk = 1; msk < 32; msk <<= 1) {
                a0 += __shfl_xor(a0, msk, 32);
                a1 += __shfl_xor(a1, msk, 32);
                a2 += __shfl_xor(a2, msk, 32);
            }
            if (ln == 0) {
                float f0, f1, f2;
                if (it == 1) { f0 = gr[0]; f1 = gr[1]; f2 = gr[2]; }
                else { f0 = sp[i * 3 + 0]; f1 = sp[i * 3 + 1]; f2 = sp[i * 3 + 2]; }
                sq[i * 3 + 0] = (n0n > 0) ? a0 / (float)n0n : f0;
                sq[i * 3 + 1] = (n1n > 0) ? a1 / (float)n1n : f1;
                sq[i * 3 + 2] = (n2n > 0) ? a2 / (float)n2n : f2;
            }
        }
        if (tid < 3) cntPrev[tid] = cnt2[tid];
        par ^= 1;
        grid.sync();
    }

    if (blockIdx.x == 0) {
        if (tid == 0) {
            st[0] = 0;
            st[1] = ((cnt2[0] + 3) >> 2) << 2;
            st[2] = st[1] + (((cnt2[1] + 3) >> 2) << 2);
            st[3] = st[2] + (((cnt2[2] + 3) >> 2) << 2);
            c2r[0] = 0; c2r[1] = 0; c2r[2] = 0;
        }
        __syncthreads();
        if (tid < SLOTS_) chlist[tid] = 0;
        if (tid < NTILES_) {
            int s = tid * 4;
            slabel[tid] = (s < st[1]) ? 0 : (s < st[2]) ? 1 : (s < st[3]) ? 2 : 0;
        }
        __syncthreads();
        if (tid < CH_) {
            int lb = lab[tid];
            int r = atomicAdd(&c2r[lb], 1);
            int slot = st[lb] + r;
            chlist[slot] = tid;
            chpos[tid] = slot;
        }
    }
}

// ---------------- K5: grouped GEMM  C[64 sb][192 p] = Z_tile . WF2[lab]^T ---
__global__ __launch_bounds__(256) void k5_grouped(const ushort* __restrict__ zLF,
                                                  const ushort* __restrict__ zUF,
                                                  const ushort* __restrict__ WF2,
                                                  const int* __restrict__ chlist,
                                                  const int* __restrict__ slabel,
                                                  const float* __restrict__ bg,
                                                  const float* __restrict__ bu,
                                                  const float* __restrict__ meanT,
                                                  const float* __restrict__ sstdT,
                                                  float* __restrict__ outP) {
    __shared__ __align__(16) ushort ZT[64][40];
    __shared__ __align__(16) ushort WT[192][40];
    __shared__ int sch[2];

    int tile = blockIdx.x;               // 0..505
    int tid = threadIdx.x;
    if (tid < 2) sch[tid] = chlist[tile * 2 + tid];
    int lab = slabel[tile >> 1];
    __syncthreads();

    int lane = tid & 63, wid = tid >> 6; // wid = p-quarter (48 p each)
    int fr = lane & 15, g8 = lane >> 4;

    int srow = tid >> 2, sseg = tid & 3; // srow 0..63
    size_t zb = (size_t)sch[srow >> 5] * KBL_ + (size_t)(srow & 31) * LH_;
    const ushort* wbase = WF2 + (size_t)(lab * PRED_) * 1024;

    f32x4 acc[4][3];
#pragma unroll
    for (int m = 0; m < 4; ++m)
#pragma unroll
        for (int n = 0; n < 3; ++n) acc[m][n] = (f32x4){0.f, 0.f, 0.f, 0.f};

    uint4 pz, pw0, pw1, pw2;
    auto stage_load = [&](int t) {
        const ushort* zsrc = (t < 16) ? zLF : zUF;
        int ko = ((t & 15) * 32) + sseg * 8;
        pz  = *(const uint4*)(zsrc + zb + ko);
        int kw = t * 32 + sseg * 8;
        pw0 = *(const uint4*)(wbase + (size_t)srow * 1024 + kw);
        pw1 = *(const uint4*)(wbase + (size_t)(srow + 64) * 1024 + kw);
        pw2 = *(const uint4*)(wbase + (size_t)(srow + 128) * 1024 + kw);
    };
    auto stage_write = [&]() {
        *(uint4*)&ZT[srow][sseg * 8] = pz;
        *(uint4*)&WT[srow][sseg * 8] = pw0;
        *(uint4*)&WT[srow + 64][sseg * 8] = pw1;
        *(uint4*)&WT[srow + 128][sseg * 8] = pw2;
    };

    stage_load(0);
    for (int t = 0; t < 32; ++t) {
        __syncthreads();
        stage_write();
        __syncthreads();
        if (t + 1 < 32) stage_load(t + 1);

        f16x8 a[4];
#pragma unroll
        for (int m = 0; m < 4; ++m)
            a[m] = *(const f16x8*)&ZT[m * 16 + fr][g8 * 8];
#pragma unroll
        for (int nf = 0; nf < 3; ++nf) {
            f16x8 bv = *(const f16x8*)&WT[wid * 48 + nf * 16 + fr][g8 * 8];
#pragma unroll
            for (int m = 0; m < 4; ++m)
                acc[m][nf] = __builtin_amdgcn_mfma_f32_16x16x32_f16(a[m], bv, acc[m][nf], 0, 0, 0);
        }
    }

#pragma unroll
    for (int m = 0; m < 4; ++m) {
#pragma unroll
        for (int q = 0; q < 4; ++q) {
            int sb = m * 16 + g8 * 4 + q;
            int sl = sb >> 5, b = sb & 31;
            int n = sch[sl];
            float sd = sstdT[n * B_ + b], mu = meanT[n * B_ + b];
            size_t obase = ((size_t)(tile * 2 + sl) * B_ + b) * PRED_;
#pragma unroll
            for (int nf = 0; nf < 3; ++nf) {
                int p = wid * 48 + nf * 16 + fr;
                float v = acc[m][nf][q] + bg[lab * PRED_ + p] + bu[p];
                outP[obase + p] = v * sd + mu;
            }
        }
    }
}

// ---------------- K7: unpermute outP -> out[b][p][n] ------------------------
__global__ __launch_bounds__(256) void k7_unperm(const float* __restrict__ outP,
                                                 const int* __restrict__ chpos,
                                                 float* __restrict__ out) {
    int n = blockIdx.x * 256 + threadIdx.x;
    int p0 = blockIdx.y * 32;
    int b = blockIdx.z;
    if (n >= CH_) return;
    const float* src = outP + ((size_t)chpos[n] * B_ + b) * PRED_ + p0;
    float4 v[8];
#pragma unroll
    for (int j = 0; j < 8; ++j) v[j] = *(const float4*)(src + j * 4);
#pragma unroll
    for (int j = 0; j < 8; ++j) {
#pragma unroll
        for (int e = 0; e < 4; ++e) {
            int p = p0 + j * 4 + e;
            out[((size_t)b * PRED_ + p) * CH_ + n] = ((const float*)&v[j])[e];
        }
    }
}

extern "C" void kernel_launch(void* const* d_in, const int* in_sizes, int n_in,
                              void* d_out, int out_size, void* d_ws, size_t ws_size,
                              hipStream_t stream) {
    const float* x  = (const float*)d_in[0];
    const float* Wg = (const float*)d_in[4];
    const float* bg = (const float*)d_in[5];
    const float* Wu = (const float*)d_in[6];
    const float* bu = (const float*)d_in[7];
    float* out = (float*)d_out;
    (void)in_sizes; (void)n_in; (void)out_size; (void)ws_size;

    char* ws = (char*)d_ws;
    size_t off = 0;
    auto alloc = [&](size_t bytes) {
        void* p = ws + off;
        off = (off + bytes + 255) & ~(size_t)255;
        return p;
    };
    ushort* zLF  = (ushort*)alloc((size_t)16384000 * 2);
    ushort* zUF  = (ushort*)alloc((size_t)16384000 * 2);
    float*  G    = (float*)alloc((size_t)1000000 * 4);
    ushort* WF2  = (ushort*)alloc((size_t)576 * 1024 * 2);
    float*  meanT = (float*)alloc((size_t)32000 * 4);
    float*  sstdT = (float*)alloc((size_t)32000 * 4);
    float*  invT  = (float*)alloc((size_t)32000 * 4);
    float*  pS   = (float*)alloc((size_t)SEG_ * B_ * CH_ * 4);
    float*  pSS  = (float*)alloc((size_t)SEG_ * B_ * CH_ * 4);
    float*  sbuf = (float*)alloc((size_t)2 * 3 * CH_ * 4);
    int*    chlist = (int*)alloc((size_t)SLOTS_ * 4);
    int*    chpos  = (int*)alloc((size_t)1024 * 4);
    int*    slabel = (int*)alloc((size_t)256 * 4);
    // union region: Gp (16*36*16384*4 = 37.7 MB, dead after k3b) then outP (24.9 MB)
    char* unionBase = (char*)alloc((size_t)ZSPLIT_ * NTRI_ * 16384 * 4);
    float* Gp   = (float*)unionBase;
    float* outP = (float*)unionBase;

    k1_fused<<<512 + 576, 256, 0, stream>>>(x, pS, pSS, Wg, Wu, WF2);
    k1b_reduce<<<125, 256, 0, stream>>>(pS, pSS, meanT, sstdT, invT);
    k2_build<<<dim3(32, 16, 32), 256, 0, stream>>>(x, meanT, invT, zLF, zUF);
    k3_mfma<<<8 * NTRI_ * 2, 256, 0, stream>>>(zLF, Gp);
    k3b_sym<<<dim3(NTRI_, 4), 256, 0, stream>>>(Gp, G);
    void* args[] = { (void*)&G, (void*)&sbuf, (void*)&chlist, (void*)&chpos, (void*)&slabel };
    hipLaunchCooperativeKernel((void*)k4_kmeans, dim3(KMB_), dim3(1024), args, 0, stream);
    k5_grouped<<<NT2_, 256, 0, stream>>>(zLF, zUF, WF2, chlist, slabel,
                                         bg, bu, meanT, sstdT, outP);
    k7_unperm<<<dim3(4, 6, 32), 256, 0, stream>>>(outP, chpos, out);
}